// Round 3
// baseline (100.815 us; speedup 1.0000x reference)
//
#include <hip/hip_runtime.h>

// PlaceCellNetwork forward: out = softmax(tanh([x,1] @ Wh^T + bh + prev @ Wf) @ Wo^T + bo)
// B=4M, IN=2, HID=20, OUT=10.
//
// R3: round-2 showed VGPR_Count=28 (can't hold ~45 live floats) -> compiler
// squeezed/spilled. This version:
//  - processes 2 rows/thread as (rowA,rowB) f32x2 pairs -> v_pk_fma_f32
//    (packed fp32, 2x VALU throughput; the 157 TF fp32 path)
//  - weights stored DUPLICATED (w,w) in d_ws so s_load yields SGPR pairs
//    directly usable as VOP3P operands (1 SGPR source per VALU op is free)
//  - algebra folded at repack time:
//      hidden: a'' = (2*log2e)*(Wh x + bh + Wf^T prev)  -> r = rcp(1+exp2(a''))
//      tanh h = 1-2r folded into logits: l' = log2e*(bo+rowsum(Wo)) - (2*log2e*Wo) r
//      softmax in exp2 domain: 2^(l'-m') / sum == softmax(l)
//    so each hidden unit is exp2+add+rcp, each exp is a bare v_exp_f32.
//  - zero runtime-indexed arrays (named scalars via macros), launch_bounds
//    (256,4) caps VGPR at 128 -> no spill possible at ~70 live regs.

#define HID 20
#define OUT 10

typedef float f32x2 __attribute__((ext_vector_type(2)));

__device__ __forceinline__ float fast_rcp(float x) { return __builtin_amdgcn_rcpf(x); }

#define EACH10(F) F(0) F(1) F(2) F(3) F(4) F(5) F(6) F(7) F(8) F(9)

// ---- weight repack ----
// per-i block of 48 floats at ws[48*i]:
//   [0:1]=(S*Wh[i][0])x2  [2:3]=(S*Wh[i][1])x2  [4:5]=(S*(Wh[i][2]+bh[i]))x2
//   [6:7]=pad  [8+2o : 9+2o]=(S*Wf[o][i])x2  [28+2o : 29+2o]=(-S*Wo[o][i])x2
// bo block: ws[960+2o : 961+2o] = (L*(bo[o]+sum_i Wo[o][i]))x2
// where S = 2*log2(e), L = log2(e).
__global__ void repack_kernel(const float* __restrict__ Wh, const float* __restrict__ bh,
                              const float* __restrict__ Wo, const float* __restrict__ bo,
                              const float* __restrict__ Wf, float* __restrict__ ws) {
    const float S = 2.8853900817779268f;  // 2*log2(e)
    const float L = 1.4426950408889634f;  // log2(e)
    int t = threadIdx.x;
    if (t < HID) {
        float* b = ws + 48 * t;
        float w0 = S * Wh[3 * t + 0];
        float w1 = S * Wh[3 * t + 1];
        float wb = S * (Wh[3 * t + 2] + bh[t]);
        b[0] = w0; b[1] = w0;
        b[2] = w1; b[3] = w1;
        b[4] = wb; b[5] = wb;
        b[6] = 0.0f; b[7] = 0.0f;
        for (int o = 0; o < OUT; ++o) {
            float wf = S * Wf[o * HID + t];
            b[8 + 2 * o] = wf; b[9 + 2 * o] = wf;
            float wo = -S * Wo[o * HID + t];   // -2*log2e*Wo
            b[28 + 2 * o] = wo; b[29 + 2 * o] = wo;
        }
    } else if (t < HID + OUT) {
        int o = t - HID;
        float s = bo[o];
        for (int i = 0; i < HID; ++i) s += Wo[o * HID + i];
        float v = L * s;
        ws[960 + 2 * o] = v; ws[961 + 2 * o] = v;
    }
}

// ---- main kernel: 2 rows/thread, packed fp32 ----
__global__ __launch_bounds__(256, 4) void pcn_kernel(
    const float* __restrict__ x, const float* __restrict__ prev,
    const float* __restrict__ w, float* __restrict__ out, int B) {
    const long t = (long)blockIdx.x * blockDim.x + threadIdx.x;
    const long r0 = 2 * t;
    if (r0 >= B) return;

#define LD2(p) (*reinterpret_cast<const f32x2*>(p))

    // inputs: aligned float4 (x: 16B/thread, prev: 80B/thread)
    const float4 xv = *reinterpret_cast<const float4*>(x + 2 * r0);  // xA0,xA1,xB0,xB1
    const f32x2 x0 = {xv.x, xv.z};
    const f32x2 x1 = {xv.y, xv.w};

    const float4* pp = reinterpret_cast<const float4*>(prev + 10 * r0);
    const float4 q0 = pp[0], q1 = pp[1], q2 = pp[2], q3 = pp[3], q4 = pp[4];
    const f32x2 p0 = {q0.x, q2.z}, p1 = {q0.y, q2.w}, p2 = {q0.z, q3.x},
                p3 = {q0.w, q3.y}, p4 = {q1.x, q3.z}, p5 = {q1.y, q3.w},
                p6 = {q1.z, q4.x}, p7 = {q1.w, q4.y}, p8 = {q2.x, q4.z},
                p9 = {q2.y, q4.w};

    // logit accumulators (exp2-domain), init = L*(bo + rowsum(Wo))
#define INITL(o) f32x2 l##o = LD2(w + 960 + 2 * o);
    EACH10(INITL)
#undef INITL

    // stream hidden units; r_i = rcp(1+2^(a'')) consumed immediately
#pragma unroll
    for (int i = 0; i < HID; ++i) {
        const float* wb = w + 48 * i;
        f32x2 a = LD2(wb + 4);
        a += LD2(wb + 0) * x0;
        a += LD2(wb + 2) * x1;
#define FB(o) a += LD2(wb + 8 + 2 * o) * p##o;
        EACH10(FB)
#undef FB
        f32x2 r;
        r.x = fast_rcp(1.0f + exp2f(a.x));
        r.y = fast_rcp(1.0f + exp2f(a.y));
#define LO(o) l##o += LD2(wb + 28 + 2 * o) * r;
        EACH10(LO)
#undef LO
    }

    // softmax in exp2 domain
    f32x2 m = l0;
#define MX(o) m.x = fmaxf(m.x, l##o.x); m.y = fmaxf(m.y, l##o.y);
    MX(1) MX(2) MX(3) MX(4) MX(5) MX(6) MX(7) MX(8) MX(9)
#undef MX
#define EX(o) l##o.x = exp2f(l##o.x - m.x); l##o.y = exp2f(l##o.y - m.y);
    EACH10(EX)
#undef EX
    const f32x2 s = ((l0 + l1) + (l2 + l3)) + (((l4 + l5) + (l6 + l7)) + (l8 + l9));
    f32x2 rs;
    rs.x = fast_rcp(s.x);
    rs.y = fast_rcp(s.y);
#define SC(o) l##o *= rs;
    EACH10(SC)
#undef SC

    // store: 5 aligned float4
    float4* op = reinterpret_cast<float4*>(out + 10 * r0);
    op[0] = make_float4(l0.x, l1.x, l2.x, l3.x);
    op[1] = make_float4(l4.x, l5.x, l6.x, l7.x);
    op[2] = make_float4(l8.x, l9.x, l0.y, l1.y);
    op[3] = make_float4(l2.y, l3.y, l4.y, l5.y);
    op[4] = make_float4(l6.y, l7.y, l8.y, l9.y);
#undef LD2
}

// ---- fallback (no workspace): 1 row/thread, straightforward ----
__global__ __launch_bounds__(256) void pcn_fallback(
    const float* __restrict__ x, const float* __restrict__ prev,
    const float* __restrict__ Wh, const float* __restrict__ bh,
    const float* __restrict__ Wo, const float* __restrict__ bo,
    const float* __restrict__ Wf, float* __restrict__ out, int B) {
    const long r = (long)blockIdx.x * blockDim.x + threadIdx.x;
    if (r >= B) return;
    const float x0 = x[2 * r], x1 = x[2 * r + 1];
#define DECLP(o) const float p##o = prev[10 * r + o];
    EACH10(DECLP)
#undef DECLP
#define DECLL(o) float l##o = bo[o];
    EACH10(DECLL)
#undef DECLL
#pragma unroll
    for (int i = 0; i < HID; ++i) {
        float a = fmaf(Wh[3 * i], x0, fmaf(Wh[3 * i + 1], x1, Wh[3 * i + 2] + bh[i]));
#define FB(o) a = fmaf(Wf[o * HID + i], p##o, a);
        EACH10(FB)
#undef FB
        const float h = 1.0f - 2.0f * fast_rcp(1.0f + __expf(2.0f * a));
#define LO(o) l##o = fmaf(Wo[o * HID + i], h, l##o);
        EACH10(LO)
#undef LO
    }
    float m = l0;
#define MX(o) m = fmaxf(m, l##o);
    MX(1) MX(2) MX(3) MX(4) MX(5) MX(6) MX(7) MX(8) MX(9)
#undef MX
    float s = 0.0f;
#define EX(o) l##o = __expf(l##o - m); s += l##o;
    EACH10(EX)
#undef EX
    const float rs = fast_rcp(s);
#define ST(o) out[10 * r + o] = l##o * rs;
    EACH10(ST)
#undef ST
}

extern "C" void kernel_launch(void* const* d_in, const int* in_sizes, int n_in,
                              void* d_out, int out_size, void* d_ws, size_t ws_size,
                              hipStream_t stream) {
    const float* x    = (const float*)d_in[0];
    const float* prev = (const float*)d_in[1];
    const float* Wh   = (const float*)d_in[2];
    const float* bh   = (const float*)d_in[3];
    const float* Wo   = (const float*)d_in[4];
    const float* bo   = (const float*)d_in[5];
    const float* Wf   = (const float*)d_in[6];
    float* out = (float*)d_out;

    const int B = in_sizes[0] / 2;

    if (ws_size >= 980 * sizeof(float)) {
        float* ws = (float*)d_ws;
        repack_kernel<<<1, 64, 0, stream>>>(Wh, bh, Wo, bo, Wf, ws);
        const int block = 256;
        const int grid = (B / 2 + block - 1) / block;  // 2 rows/thread
        pcn_kernel<<<grid, block, 0, stream>>>(x, prev, ws, out, B);
    } else {
        const int block = 256;
        const int grid = (B + block - 1) / block;
        pcn_fallback<<<grid, block, 0, stream>>>(x, prev, Wh, bh, Wo, bo, Wf, out, B);
    }
}